// Round 12
// baseline (699.326 us; speedup 1.0000x reference)
//
#include <hip/hip_runtime.h>
#include <math.h>

typedef unsigned short ushort_t;
typedef __bf16 bf16x8 __attribute__((ext_vector_type(8)));
typedef float f32x4 __attribute__((ext_vector_type(4)));

__device__ __forceinline__ float bf2f(unsigned int u) {
    union { unsigned int i; float f; } v; v.i = u << 16; return v.f;
}
__device__ __forceinline__ ushort_t f2bf(float f) {
    union { float f; unsigned int i; } v; v.f = f;
    unsigned int u = v.i;
    unsigned int r = u + 0x7fffu + ((u >> 16) & 1u);
    return (ushort_t)(r >> 16);
}
// HW RTNE bf16 cast (single v_cvt; bit-identical to f2bf for finite inputs)
__device__ __forceinline__ ushort_t f2bf_hw(float f) {
    union { __bf16 h; ushort_t u; } v; v.h = (__bf16)f; return v.u;
}

// DPP row-rotate (16-lane rows) for cross-lane reduce without LDS pipe.
template <int N>
__device__ __forceinline__ float ror16f(float x) {
    union { float f; int i; } u; u.f = x;
    u.i = __builtin_amdgcn_mov_dpp(u.i, 0x120 + N, 0xF, 0xF, true);
    return u.f;
}

// async global->LDS, 16B per lane. Dest must be linear: base + lane*16.
__device__ __forceinline__ void gload16(const ushort_t* g, ushort_t* l) {
    __builtin_amdgcn_global_load_lds(
        (__attribute__((address_space(1))) void*)g,
        (__attribute__((address_space(3))) void*)l, 16, 0, 0);
}

// ---------------------------------------------------------------------------
// fp32 -> bf16 elementwise (activations). 8 elems/thread.
// ---------------------------------------------------------------------------
__global__ void __launch_bounds__(256) cvt_bf16_kernel(
    const float* __restrict__ in, ushort_t* __restrict__ out, int n8)
{
    int i = blockIdx.x * 256 + threadIdx.x;
    if (i >= n8) return;
    size_t off = (size_t)i * 8;
    float4 a = *(const float4*)(in + off);
    float4 b = *(const float4*)(in + off + 4);
    ushort_t o[8] = {f2bf(a.x), f2bf(a.y), f2bf(a.z), f2bf(a.w),
                     f2bf(b.x), f2bf(b.y), f2bf(b.z), f2bf(b.w)};
    *(uint4*)(out + off) = *(const uint4*)o;
}

// ---------------------------------------------------------------------------
// W [K,N] fp32 -> Wt [N,K] bf16 (transpose+convert), 32x32 LDS tiles.
// ---------------------------------------------------------------------------
__global__ void __launch_bounds__(256) wconv_kernel(
    const float* __restrict__ W, ushort_t* __restrict__ Wt, int K, int N)
{
    __shared__ float tile[32][33];
    const int t = threadIdx.x;
    const int k0 = blockIdx.x * 32, n0 = blockIdx.y * 32;
    const int r = t >> 3, c4 = (t & 7) * 4;
    float4 d = *(const float4*)(&W[(size_t)(k0 + r) * N + n0 + c4]);
    tile[r][c4 + 0] = d.x; tile[r][c4 + 1] = d.y;
    tile[r][c4 + 2] = d.z; tile[r][c4 + 3] = d.w;
    __syncthreads();
    ushort_t o[4] = { f2bf(tile[c4 + 0][r]), f2bf(tile[c4 + 1][r]),
                      f2bf(tile[c4 + 2][r]), f2bf(tile[c4 + 3][r]) };
    *(uint2*)(&Wt[(size_t)(n0 + r) * K + k0 + c4]) = *(const uint2*)o;
}

// ---------------------------------------------------------------------------
// GEMM (B^T form): C[M,N] = A[M,K](bf16) @ Bt[N,K](bf16)^T + bias.
// BMT in {64,128}, BNT in {64,128}, BKT in {32,64}, 4 waves (2x2),
// mfma_f32_16x16x32_bf16. T4 counted-vmcnt schedule with RAW s_barrier
// (NOT __syncthreads, which emits vmcnt(0) before s_barrier):
//   issue stage(t+1) -> vmcnt(LPT) [tile-t loads retired, FIFO per m135]
//   -> raw barrier -> ds_read+MFMA -> raw barrier.
// BMT=64 for the skinny N=1024 shapes: grid 512->1024+ blocks, LDS
// 48->32 KB -> 5 resident blocks/CU (was 2) -> TLP hides staging (m114).
// blockIdx.z selects one of up to 3 (W,bias,C) sets. MODE 2 adds exact GELU.
// ---------------------------------------------------------------------------
template <int MODE, int BMT, int BNT, int BKT>
__global__ void __launch_bounds__(256) gemm_bt_kernel(
    const ushort_t* __restrict__ A,
    const ushort_t* __restrict__ B0, const ushort_t* __restrict__ B1,
    const ushort_t* __restrict__ B2,
    const float* __restrict__ bias0, const float* __restrict__ bias1,
    const float* __restrict__ bias2,
    ushort_t* __restrict__ C0, ushort_t* __restrict__ C1,
    ushort_t* __restrict__ C2,
    int M, int N, int K)
{
    __shared__ __align__(16) ushort_t As[2][BMT * BKT];
    __shared__ __align__(16) ushort_t Bs[2][BNT * BKT];

    constexpr int WM = BMT / 2;       // per-wave M extent (32 or 64)
    constexpr int MIF = WM / 16;      // M frags per wave (2 or 4)
    constexpr int WN = BNT / 2;       // per-wave N extent
    constexpr int NJF = WN / 16;      // N frags per wave (2 or 4)
    constexpr int KK = BKT / 32;      // K sub-steps per tile (1 or 2)
    constexpr int CPR = BKT / 8;      // 16B chunks per row
    constexpr int PA = BMT * BKT / 2048;  // staging passes for A
    constexpr int PB = BNT * BKT / 2048;  // staging passes for B
    constexpr int LPT = PA + PB;          // loads per tile per thread

    const int z = blockIdx.z;
    const ushort_t* Bt = (z == 0) ? B0 : ((z == 1) ? B1 : B2);
    const float* bias = (z == 0) ? bias0 : ((z == 1) ? bias1 : bias2);
    ushort_t* Cout = (z == 0) ? C0 : ((z == 1) ? C1 : C2);

    const int tid = threadIdx.x;
    const int m0 = blockIdx.y * BMT, n0 = blockIdx.x * BNT;
    const int wave = tid >> 6, lane = tid & 63;
    const int wm = wave >> 1, wn = wave & 1;
    const int lr = lane & 15;
    const int lk = (lane >> 4) * 8;

    const ushort_t* Ab = A + (size_t)m0 * K;
    const ushort_t* Bb = Bt + (size_t)n0 * K;

    f32x4 acc[MIF][NJF];
#pragma unroll
    for (int i = 0; i < MIF; i++)
#pragma unroll
        for (int j = 0; j < NJF; j++) acc[i][j] = (f32x4){0.f, 0.f, 0.f, 0.f};

    const int nt = K / BKT;

    auto stage = [&](int buf, int t) {
#pragma unroll
        for (int p = 0; p < PA; p++) {
            int v = p * 256 + tid;
            int row = v / CPR, c = v % CPR;
            gload16(Ab + (size_t)row * K + (size_t)t * BKT + c * 8,
                    &As[buf][v * 8]);
        }
#pragma unroll
        for (int p = 0; p < PB; p++) {
            int v = p * 256 + tid;
            int row = v / CPR, c = v % CPR;
            gload16(Bb + (size_t)row * K + (size_t)t * BKT + c * 8,
                    &Bs[buf][v * 8]);
        }
    };

    // prologue: tile 0 into buffer 0 (loads left in flight; counted below)
    stage(0, 0);

    for (int t = 0; t < nt; ++t) {
        const int p = t & 1;
        if (t + 1 < nt) {
            stage(p ^ 1, t + 1);   // issue next tile (stays in flight)
            // FIFO vmcnt: allow the newest LPT (tile t+1) outstanding;
            // this retires all of THIS wave's tile-t loads.
            asm volatile("s_waitcnt vmcnt(%0)" :: "n"(LPT) : "memory");
        } else {
            asm volatile("s_waitcnt vmcnt(0)" ::: "memory");
        }
        __builtin_amdgcn_s_barrier();   // raw: no implicit drain

        bf16x8 af[MIF][KK], bfr[NJF][KK];
#pragma unroll
        for (int i = 0; i < MIF; i++)
#pragma unroll
            for (int kk = 0; kk < KK; kk++)
                af[i][kk] = *(const bf16x8*)(&As[p][(wm * WM + i * 16 + lr) * BKT + kk * 32 + lk]);
#pragma unroll
        for (int j = 0; j < NJF; j++)
#pragma unroll
            for (int kk = 0; kk < KK; kk++)
                bfr[j][kk] = *(const bf16x8*)(&Bs[p][(wn * WN + j * 16 + lr) * BKT + kk * 32 + lk]);
#pragma unroll
        for (int kk = 0; kk < KK; kk++)
#pragma unroll
            for (int i = 0; i < MIF; i++)
#pragma unroll
                for (int j = 0; j < NJF; j++)
                    acc[i][j] = __builtin_amdgcn_mfma_f32_16x16x32_bf16(af[i][kk], bfr[j][kk], acc[i][j], 0, 0, 0);

        // All of this wave's ds_reads of buf[p] retired (compiler lgkmcnt
        // before MFMA use). Raw barrier: after it, nobody reads buf[p],
        // so next iter's stage may overwrite it.
        asm volatile("" ::: "memory");
        __builtin_amdgcn_s_barrier();
    }

    const int rq = (lane >> 4) * 4;
#pragma unroll
    for (int j = 0; j < NJF; j++) {
        const int col = n0 + wn * WN + j * 16 + lr;
        const float bv = bias[col];
#pragma unroll
        for (int i = 0; i < MIF; i++) {
#pragma unroll
            for (int r = 0; r < 4; r++) {
                const int row = m0 + wm * WM + i * 16 + rq + r;
                float v = acc[i][j][r] + bv;
                if (MODE == 2) {
                    v = 0.5f * v * (1.0f + erff(v * 0.70710678118654752f));
                }
                Cout[(size_t)row * N + col] = f2bf(v);
            }
        }
    }
}

// ---------------------------------------------------------------------------
// MFMA flash attention. hd=64, D=1024, H=16. Q/K/V bf16 ws [b,l,h*64+d].
// Block: 256 thr = 4 waves, one (b,h), 64 q rows (16/wave). KVBLK=64.
// Reg-prefetch staging; XCD-swizzled block map (16 q-tiles/bh -> one XCD).
// Softmax reductions via DPP row_ror; HW bf16 cvt. Grid MUST be (16, 64).
// Unchanged from R7/R10/R11.
// ---------------------------------------------------------------------------
__global__ void __launch_bounds__(256) mfma_attn_kernel(
    const ushort_t* __restrict__ Q, const ushort_t* __restrict__ Kt,
    const ushort_t* __restrict__ Vt, const float* __restrict__ mask,
    ushort_t* __restrict__ O, int Lq, int Lk, float scale)
{
    __shared__ __align__(16) ushort_t qs[64][72];
    __shared__ __align__(16) ushort_t ks[64][72];
    __shared__ __align__(16) ushort_t vsT[64][72];   // [d][k ^ swz(d)]
    __shared__ __align__(16) ushort_t ps[4][16][72]; // per-wave P [q][k]

    const int tid = threadIdx.x;
    const int wave = tid >> 6, lane = tid & 63;
    const int quad = lane >> 4, lc = lane & 15;

    const int id = blockIdx.x + (int)gridDim.x * blockIdx.y;  // 0..1023
    const int bh = (id & 7) * 8 + ((id >> 3) >> 4);
    const int qt = (id >> 3) & 15;
    const int b = bh >> 4, h = bh & 15;
    const int q0 = qt * 64;
    const size_t qbase = ((size_t)b * Lq) * 1024 + h * 64;
    const size_t kbase = ((size_t)b * Lk) * 1024 + h * 64;
    const float* maskb = mask ? (mask + (size_t)b * Lk) : nullptr;

#pragma unroll
    for (int r = 0; r < 2; r++) {
        int v = r * 256 + tid;
        int row = v >> 3, c8 = (v & 7) * 8;
        *(uint4*)(&qs[row][c8]) = *(const uint4*)(&Q[qbase + (size_t)(q0 + row) * 1024 + c8]);
    }
    __syncthreads();

    bf16x8 qa0 = *(const bf16x8*)(&qs[wave * 16 + lc][quad * 8]);
    bf16x8 qa1 = *(const bf16x8*)(&qs[wave * 16 + lc][32 + quad * 8]);

    f32x4 o[4];
#pragma unroll
    for (int d = 0; d < 4; d++) o[d] = (f32x4){0.f, 0.f, 0.f, 0.f};
    float m_i[4], l_i[4];
#pragma unroll
    for (int r = 0; r < 4; r++) { m_i[r] = -1e30f; l_i[r] = 0.f; }

    const int sr = tid >> 2;
    const int d0c = (tid & 3) * 16;
    const int vswz = (tid & 3) << 3;
    const int vcol = sr ^ vswz;

    const int nt = Lk >> 6;
    size_t gk = kbase + (size_t)sr * 1024 + d0c;

    uint4 kA = *(const uint4*)(Kt + gk);
    uint4 kB = *(const uint4*)(Kt + gk + 8);
    uint4 vA = *(const uint4*)(Vt + gk);
    uint4 vB = *(const uint4*)(Vt + gk + 8);

    for (int t = 0; t < nt; ++t) {
        const int kt = t << 6;
        __syncthreads();
        *(uint4*)(&ks[sr][d0c])     = kA;
        *(uint4*)(&ks[sr][d0c + 8]) = kB;
        {
            const ushort_t* vp = (const ushort_t*)&vA;
            const ushort_t* wp = (const ushort_t*)&vB;
#pragma unroll
            for (int i = 0; i < 8; i++) vsT[d0c + i][vcol]     = vp[i];
#pragma unroll
            for (int i = 0; i < 8; i++) vsT[d0c + 8 + i][vcol] = wp[i];
        }
        if (t + 1 < nt) {
            gk += 64 * 1024;
            kA = *(const uint4*)(Kt + gk);
            kB = *(const uint4*)(Kt + gk + 8);
            vA = *(const uint4*)(Vt + gk);
            vB = *(const uint4*)(Vt + gk + 8);
        }
        __syncthreads();

        float mk[4];
#pragma unroll
        for (int g = 0; g < 4; g++)
            mk[g] = maskb ? maskb[kt + g * 16 + lc] : 0.f;

        f32x4 s[4];
        __builtin_amdgcn_s_setprio(1);
#pragma unroll
        for (int g = 0; g < 4; g++) {
            bf16x8 k0 = *(const bf16x8*)(&ks[g * 16 + lc][quad * 8]);
            bf16x8 k1 = *(const bf16x8*)(&ks[g * 16 + lc][32 + quad * 8]);
            f32x4 zz = (f32x4){0.f, 0.f, 0.f, 0.f};
            zz = __builtin_amdgcn_mfma_f32_16x16x32_bf16(qa0, k0, zz, 0, 0, 0);
            zz = __builtin_amdgcn_mfma_f32_16x16x32_bf16(qa1, k1, zz, 0, 0, 0);
            s[g] = zz;
        }
        __builtin_amdgcn_s_setprio(0);

        // online softmax; reductions over the 16 lanes of this quad via DPP
        float alpha[4];
#pragma unroll
        for (int r = 0; r < 4; r++) {
            float v0 = s[0][r] * scale + mk[0];
            float v1 = s[1][r] * scale + mk[1];
            float v2 = s[2][r] * scale + mk[2];
            float v3 = s[3][r] * scale + mk[3];
            float mx = fmaxf(fmaxf(v0, v1), fmaxf(v2, v3));
            mx = fmaxf(mx, ror16f<1>(mx));
            mx = fmaxf(mx, ror16f<2>(mx));
            mx = fmaxf(mx, ror16f<4>(mx));
            mx = fmaxf(mx, ror16f<8>(mx));
            float mnew = fmaxf(m_i[r], mx);
            alpha[r] = __expf(m_i[r] - mnew);
            m_i[r] = mnew;
            float p0 = __expf(v0 - mnew);
            float p1 = __expf(v1 - mnew);
            float p2 = __expf(v2 - mnew);
            float p3 = __expf(v3 - mnew);
            ps[wave][quad * 4 + r][lc]      = f2bf_hw(p0);
            ps[wave][quad * 4 + r][16 + lc] = f2bf_hw(p1);
            ps[wave][quad * 4 + r][32 + lc] = f2bf_hw(p2);
            ps[wave][quad * 4 + r][48 + lc] = f2bf_hw(p3);
            float psum = (p0 + p1) + (p2 + p3);
            psum += ror16f<1>(psum);
            psum += ror16f<2>(psum);
            psum += ror16f<4>(psum);
            psum += ror16f<8>(psum);
            l_i[r] = l_i[r] * alpha[r] + psum;
        }
#pragma unroll
        for (int d = 0; d < 4; d++)
#pragma unroll
            for (int r = 0; r < 4; r++) o[d][r] *= alpha[r];

        __builtin_amdgcn_s_setprio(1);
#pragma unroll
        for (int kk = 0; kk < 2; kk++) {
            bf16x8 pa = *(const bf16x8*)(&ps[wave][lc][kk * 32 + quad * 8]);
#pragma unroll
            for (int d = 0; d < 4; d++) {
                int dr = d * 16 + lc;
                bf16x8 vb = *(const bf16x8*)(&vsT[dr][(kk * 32 + quad * 8) ^ (d << 3)]);
                o[d] = __builtin_amdgcn_mfma_f32_16x16x32_bf16(pa, vb, o[d], 0, 0, 0);
            }
        }
        __builtin_amdgcn_s_setprio(0);
    }

#pragma unroll
    for (int d = 0; d < 4; d++) {
#pragma unroll
        for (int r = 0; r < 4; r++) {
            float val = o[d][r] / l_i[r];
            O[qbase + (size_t)(q0 + wave * 16 + quad * 4 + r) * 1024 + d * 16 + lc] = f2bf_hw(val);
        }
    }
}

// ---------------------------------------------------------------------------
// Fused residual + LayerNorm (rows of 1024). Unchanged.
// ---------------------------------------------------------------------------
template <bool RES_F32, bool OUT_F32>
__global__ void __launch_bounds__(256) ln_kernel(
    const ushort_t* __restrict__ Hbuf, const void* __restrict__ Res,
    const float* __restrict__ gamma, const float* __restrict__ beta,
    void* __restrict__ Out)
{
    const int row = blockIdx.x;
    const int tid = threadIdx.x;
    const size_t base = (size_t)row * 1024 + tid * 4;

    uint2 hh = *(const uint2*)(Hbuf + base);
    float v[4];
    v[0] = bf2f(hh.x & 0xffffu);
    v[1] = bf2f(hh.x >> 16);
    v[2] = bf2f(hh.y & 0xffffu);
    v[3] = bf2f(hh.y >> 16);
    if (RES_F32) {
        float4 rv = *(const float4*)((const float*)Res + base);
        v[0] += rv.x; v[1] += rv.y; v[2] += rv.z; v[3] += rv.w;
    } else {
        uint2 rr = *(const uint2*)((const ushort_t*)Res + base);
        v[0] += bf2f(rr.x & 0xffffu);
        v[1] += bf2f(rr.x >> 16);
        v[2] += bf2f(rr.y & 0xffffu);
        v[3] += bf2f(rr.y >> 16);
    }

    float s = v[0] + v[1] + v[2] + v[3];
    float s2 = v[0]*v[0] + v[1]*v[1] + v[2]*v[2] + v[3]*v[3];
#pragma unroll
    for (int o = 1; o < 64; o <<= 1) {
        s += __shfl_xor(s, o, 64);
        s2 += __shfl_xor(s2, o, 64);
    }
    __shared__ float red[8];
    const int wv = tid >> 6, ln_ = tid & 63;
    if (ln_ == 0) { red[wv] = s; red[wv + 4] = s2; }
    __syncthreads();
    s = red[0] + red[1] + red[2] + red[3];
    s2 = red[4] + red[5] + red[6] + red[7];
    const float mu = s * (1.0f / 1024.0f);
    const float var = s2 * (1.0f / 1024.0f) - mu * mu;
    const float rstd = rsqrtf(var + 1e-5f);

    float4 gv = *(const float4*)(&gamma[tid * 4]);
    float4 bv = *(const float4*)(&beta[tid * 4]);
    float o0 = (v[0] - mu) * rstd * gv.x + bv.x;
    float o1 = (v[1] - mu) * rstd * gv.y + bv.y;
    float o2 = (v[2] - mu) * rstd * gv.z + bv.z;
    float o3 = (v[3] - mu) * rstd * gv.w + bv.w;

    if (OUT_F32) {
        float4 of = {o0, o1, o2, o3};
        *(float4*)((float*)Out + base) = of;
    } else {
        ushort_t ob[4] = {f2bf(o0), f2bf(o1), f2bf(o2), f2bf(o3)};
        *(uint2*)((ushort_t*)Out + base) = *(uint2*)ob;
    }
}

// ---------------------------------------------------------------------------
// Launch. ws layout (72 MB total, phase-local aliasing):
//   0-8   Bq            (FFN phase: WtG = fi^T / fo^T, Bq dead)
//   8-24  Bk            (FFN phase: Bi [8,40))
//   24-40 Bv
//   40-56 Xctx early -> Ba[40,48) + Bh[48,56)
//   56-64 Bx1           (cross phase, pre-LN: WtA/WtB/WtC @56/58/60)
//   64-72 Xin early -> (self phase: WtD/WtE/WtF @64/66/68) -> Bx2
// ---------------------------------------------------------------------------
extern "C" void kernel_launch(void* const* d_in, const int* in_sizes, int n_in,
                              void* d_out, int out_size, void* d_ws, size_t ws_size,
                              hipStream_t stream)
{
    const float* input = (const float*)d_in[0];
    const float* ctx   = (const float*)d_in[1];
    const float* mask  = (const float*)d_in[2];
    const float* cq_w = (const float*)d_in[3],  *cq_b = (const float*)d_in[4];
    const float* ck_w = (const float*)d_in[5],  *ck_b = (const float*)d_in[6];
    const float* cv_w = (const float*)d_in[7],  *cv_b = (const float*)d_in[8];
    const float* co_w = (const float*)d_in[9],  *co_b = (const float*)d_in[10];
    const float* co_g = (const float*)d_in[11], *co_be = (const float*)d_in[12];
    const float* sq_w = (const float*)d_in[13], *sq_b = (const float*)d_in[14];
    const float* sk_w = (const float*)d_in[15], *sk_b = (const float*)d_in[16];
    const float* sv_w = (const float*)d_in[17], *sv_b = (const float*)d_in[18];
    const float* so_w = (const float*)d_in[19], *so_b = (const float*)d_in[20];
    const float* so_g = (const float*)d_in[21], *so_be = (const float*)d_in[22];
    const float* fi_w = (const float*)d_in[23], *fi_b = (const float*)d_in[24];
    const float* fo_w = (const float*)d_in[25], *fo_b = (const float*)d_in[26];
    const float* fo_g = (const float*)d_in[27], *fo_be = (const float*)d_in[28];

    char* p = (char*)d_ws;
    const size_t MB = 1024 * 1024;
    ushort_t* Bq   = (ushort_t*)(p + 0 * MB);
    ushort_t* Bk   = (ushort_t*)(p + 8 * MB);
    ushort_t* Bv   = (ushort_t*)(p + 24 * MB);
    ushort_t* Ba   = (ushort_t*)(p + 40 * MB);
    ushort_t* Bh   = (ushort_t*)(p + 48 * MB);
    ushort_t* Bx1  = (ushort_t*)(p + 56 * MB);
    ushort_t* Bx2  = (ushort_t*)(p + 64 * MB);
    ushort_t* Bi   = Bk;                       // [8,40) during FFN
    ushort_t* Xctx = Ba;                       // [40,56) early only
    ushort_t* Xin  = Bx2;                      // [64,72) early only
    ushort_t* WtA  = (ushort_t*)(p + 56 * MB); // cross-phase W^T scratch
    ushort_t* WtB  = (ushort_t*)(p + 58 * MB);
    ushort_t* WtC  = (ushort_t*)(p + 60 * MB);
    ushort_t* WtD  = (ushort_t*)(p + 64 * MB); // self-phase W^T scratch
    ushort_t* WtE  = (ushort_t*)(p + 66 * MB);
    ushort_t* WtF  = (ushort_t*)(p + 68 * MB);
    ushort_t* WtG  = (ushort_t*)(p + 0 * MB);  // FFN-phase W^T scratch (8 MB)

    const float scale = 0.125f;
    dim3 blk(256);

    // ---- activation conversions ----
    cvt_bf16_kernel<<<2048, blk, 0, stream>>>(input, Xin, 524288);
    cvt_bf16_kernel<<<4096, blk, 0, stream>>>(ctx, Xctx, 1048576);

    // ---- cross attention ----
    wconv_kernel<<<dim3(32, 32), blk, 0, stream>>>(cq_w, WtA, 1024, 1024);
    wconv_kernel<<<dim3(32, 32), blk, 0, stream>>>(ck_w, WtB, 1024, 1024);
    wconv_kernel<<<dim3(32, 32), blk, 0, stream>>>(cv_w, WtC, 1024, 1024);
    gemm_bt_kernel<0, 64, 64, 64><<<dim3(16, 64, 1), blk, 0, stream>>>(
        Xin, WtA, WtA, WtA, cq_b, cq_b, cq_b, Bq, Bq, Bq, 4096, 1024, 1024);
    gemm_bt_kernel<0, 64, 64, 64><<<dim3(16, 128, 2), blk, 0, stream>>>(
        Xctx, WtB, WtC, WtC, ck_b, cv_b, cv_b, Bk, Bv, Bv, 8192, 1024, 1024);
    mfma_attn_kernel<<<dim3(16, 64), blk, 0, stream>>>(Bq, Bk, Bv, mask, Ba, 1024, 2048, scale);
    wconv_kernel<<<dim3(32, 32), blk, 0, stream>>>(co_w, WtA, 1024, 1024);
    gemm_bt_kernel<0, 64, 64, 64><<<dim3(16, 64, 1), blk, 0, stream>>>(
        Ba, WtA, WtA, WtA, co_b, co_b, co_b, Bh, Bh, Bh, 4096, 1024, 1024);
    ln_kernel<true, false><<<dim3(4096), blk, 0, stream>>>(Bh, input, co_g, co_be, Bx1);

    // ---- self attention ----
    wconv_kernel<<<dim3(32, 32), blk, 0, stream>>>(sq_w, WtD, 1024, 1024);
    wconv_kernel<<<dim3(32, 32), blk, 0, stream>>>(sk_w, WtE, 1024, 1024);
    wconv_kernel<<<dim3(32, 32), blk, 0, stream>>>(sv_w, WtF, 1024, 1024);
    gemm_bt_kernel<0, 64, 64, 64><<<dim3(16, 64, 3), blk, 0, stream>>>(
        Bx1, WtD, WtE, WtF, sq_b, sk_b, sv_b, Bq, Bk, Bv, 4096, 1024, 1024);
    mfma_attn_kernel<<<dim3(16, 64), blk, 0, stream>>>(Bq, Bk, Bv, nullptr, Ba, 1024, 1024, scale);
    wconv_kernel<<<dim3(32, 32), blk, 0, stream>>>(so_w, WtD, 1024, 1024);
    gemm_bt_kernel<0, 64, 64, 64><<<dim3(16, 64, 1), blk, 0, stream>>>(
        Ba, WtD, WtD, WtD, so_b, so_b, so_b, Bh, Bh, Bh, 4096, 1024, 1024);
    ln_kernel<false, false><<<dim3(4096), blk, 0, stream>>>(Bh, Bx1, so_g, so_be, Bx2);

    // ---- FFN ----
    wconv_kernel<<<dim3(32, 128), blk, 0, stream>>>(fi_w, WtG, 1024, 4096);
    gemm_bt_kernel<2, 128, 128, 32><<<dim3(32, 32, 1), blk, 0, stream>>>(
        Bx2, WtG, WtG, WtG, fi_b, fi_b, fi_b, Bi, Bi, Bi, 4096, 4096, 1024);
    wconv_kernel<<<dim3(128, 32), blk, 0, stream>>>(fo_w, WtG, 4096, 1024);
    gemm_bt_kernel<0, 64, 64, 64><<<dim3(16, 64, 1), blk, 0, stream>>>(
        Bi, WtG, WtG, WtG, fo_b, fo_b, fo_b, Bh, Bh, Bh, 4096, 1024, 4096);
    ln_kernel<false, true><<<dim3(4096), blk, 0, stream>>>(Bh, Bx2, fo_g, fo_be, (float*)d_out);
}

// Round 14
// 665.650 us; speedup vs baseline: 1.0506x; 1.0506x over previous
//
#include <hip/hip_runtime.h>
#include <math.h>

typedef unsigned short ushort_t;
typedef __bf16 bf16x8 __attribute__((ext_vector_type(8)));
typedef float f32x4 __attribute__((ext_vector_type(4)));

__device__ __forceinline__ float bf2f(unsigned int u) {
    union { unsigned int i; float f; } v; v.i = u << 16; return v.f;
}
__device__ __forceinline__ ushort_t f2bf(float f) {
    union { float f; unsigned int i; } v; v.f = f;
    unsigned int u = v.i;
    unsigned int r = u + 0x7fffu + ((u >> 16) & 1u);
    return (ushort_t)(r >> 16);
}
// HW RTNE bf16 cast (single v_cvt; bit-identical to f2bf for finite inputs)
__device__ __forceinline__ ushort_t f2bf_hw(float f) {
    union { __bf16 h; ushort_t u; } v; v.h = (__bf16)f; return v.u;
}

// DPP row-rotate (16-lane rows) for cross-lane reduce without LDS pipe.
template <int N>
__device__ __forceinline__ float ror16f(float x) {
    union { float f; int i; } u; u.f = x;
    u.i = __builtin_amdgcn_mov_dpp(u.i, 0x120 + N, 0xF, 0xF, true);
    return u.f;
}

// async global->LDS, 16B per lane. Dest must be linear: base + lane*16.
__device__ __forceinline__ void gload16(const ushort_t* g, ushort_t* l) {
    __builtin_amdgcn_global_load_lds(
        (__attribute__((address_space(1))) void*)g,
        (__attribute__((address_space(3))) void*)l, 16, 0, 0);
}

// ---------------------------------------------------------------------------
// fp32 -> bf16 elementwise (activations). 8 elems/thread.
// ---------------------------------------------------------------------------
__global__ void __launch_bounds__(256) cvt_bf16_kernel(
    const float* __restrict__ in, ushort_t* __restrict__ out, int n8)
{
    int i = blockIdx.x * 256 + threadIdx.x;
    if (i >= n8) return;
    size_t off = (size_t)i * 8;
    float4 a = *(const float4*)(in + off);
    float4 b = *(const float4*)(in + off + 4);
    ushort_t o[8] = {f2bf(a.x), f2bf(a.y), f2bf(a.z), f2bf(a.w),
                     f2bf(b.x), f2bf(b.y), f2bf(b.z), f2bf(b.w)};
    *(uint4*)(out + off) = *(const uint4*)o;
}

// ---------------------------------------------------------------------------
// W [K,N] fp32 -> Wt [N,K] bf16 (transpose+convert), 32x32 LDS tiles.
// ---------------------------------------------------------------------------
__global__ void __launch_bounds__(256) wconv_kernel(
    const float* __restrict__ W, ushort_t* __restrict__ Wt, int K, int N)
{
    __shared__ float tile[32][33];
    const int t = threadIdx.x;
    const int k0 = blockIdx.x * 32, n0 = blockIdx.y * 32;
    const int r = t >> 3, c4 = (t & 7) * 4;
    float4 d = *(const float4*)(&W[(size_t)(k0 + r) * N + n0 + c4]);
    tile[r][c4 + 0] = d.x; tile[r][c4 + 1] = d.y;
    tile[r][c4 + 2] = d.z; tile[r][c4 + 3] = d.w;
    __syncthreads();
    ushort_t o[4] = { f2bf(tile[c4 + 0][r]), f2bf(tile[c4 + 1][r]),
                      f2bf(tile[c4 + 2][r]), f2bf(tile[c4 + 3][r]) };
    *(uint2*)(&Wt[(size_t)(n0 + r) * K + k0 + c4]) = *(const uint2*)o;
}

// ---------------------------------------------------------------------------
// GEMM (B^T form): C[M,N] = A[M,K](bf16) @ Bt[N,K](bf16)^T + bias.
// BMT=128, BNT in {64,128}, BKT in {32,64}, 4 waves (2x2),
// mfma_f32_16x16x32_bf16. T4 counted-vmcnt schedule with RAW s_barrier:
//   issue stage(t+1) -> vmcnt(LPT) [tile-t loads retired, FIFO per m135]
//   -> raw barrier -> ds_read+MFMA -> raw barrier.
// R12 lesson: BMT=64 regressed (halved per-block MFMA work, same staging
// cadence) — keep BMT=128. Per-z (A, M) lets independent GEMMs with
// different A matrices batch into one launch (cross-QKV: cq + ck + cv).
// Padding blocks (m0 >= Mz) exit before any barrier — whole block exits
// together, so barrier participation stays consistent.
// blockIdx.z selects (A,M,W,bias,C). MODE 2 adds exact GELU.
// ---------------------------------------------------------------------------
template <int MODE, int BMT, int BNT, int BKT>
__global__ void __launch_bounds__(256) gemm_bt_kernel(
    const ushort_t* __restrict__ A0, const ushort_t* __restrict__ A1,
    int M0, int M1,
    const ushort_t* __restrict__ B0, const ushort_t* __restrict__ B1,
    const ushort_t* __restrict__ B2,
    const float* __restrict__ bias0, const float* __restrict__ bias1,
    const float* __restrict__ bias2,
    ushort_t* __restrict__ C0, ushort_t* __restrict__ C1,
    ushort_t* __restrict__ C2,
    int N, int K)
{
    __shared__ __align__(16) ushort_t As[2][BMT * BKT];
    __shared__ __align__(16) ushort_t Bs[2][BNT * BKT];

    constexpr int WM = BMT / 2;       // per-wave M extent
    constexpr int MIF = WM / 16;      // M frags per wave
    constexpr int WN = BNT / 2;       // per-wave N extent
    constexpr int NJF = WN / 16;      // N frags per wave
    constexpr int KK = BKT / 32;      // K sub-steps per tile
    constexpr int CPR = BKT / 8;      // 16B chunks per row
    constexpr int PA = BMT * BKT / 2048;  // staging passes for A
    constexpr int PB = BNT * BKT / 2048;  // staging passes for B
    constexpr int LPT = PA + PB;          // loads per tile per thread

    const int z = blockIdx.z;
    const ushort_t* A = (z == 0) ? A0 : A1;
    const int Mz = (z == 0) ? M0 : M1;
    const ushort_t* Bt = (z == 0) ? B0 : ((z == 1) ? B1 : B2);
    const float* bias = (z == 0) ? bias0 : ((z == 1) ? bias1 : bias2);
    ushort_t* Cout = (z == 0) ? C0 : ((z == 1) ? C1 : C2);

    const int tid = threadIdx.x;
    const int m0 = blockIdx.y * BMT, n0 = blockIdx.x * BNT;
    if (m0 >= Mz) return;   // merged-launch padding blocks
    const int wave = tid >> 6, lane = tid & 63;
    const int wm = wave >> 1, wn = wave & 1;
    const int lr = lane & 15;
    const int lk = (lane >> 4) * 8;

    const ushort_t* Ab = A + (size_t)m0 * K;
    const ushort_t* Bb = Bt + (size_t)n0 * K;

    f32x4 acc[MIF][NJF];
#pragma unroll
    for (int i = 0; i < MIF; i++)
#pragma unroll
        for (int j = 0; j < NJF; j++) acc[i][j] = (f32x4){0.f, 0.f, 0.f, 0.f};

    const int nt = K / BKT;

    auto stage = [&](int buf, int t) {
#pragma unroll
        for (int p = 0; p < PA; p++) {
            int v = p * 256 + tid;
            int row = v / CPR, c = v % CPR;
            gload16(Ab + (size_t)row * K + (size_t)t * BKT + c * 8,
                    &As[buf][v * 8]);
        }
#pragma unroll
        for (int p = 0; p < PB; p++) {
            int v = p * 256 + tid;
            int row = v / CPR, c = v % CPR;
            gload16(Bb + (size_t)row * K + (size_t)t * BKT + c * 8,
                    &Bs[buf][v * 8]);
        }
    };

    // prologue: tile 0 into buffer 0 (loads left in flight; counted below)
    stage(0, 0);

    for (int t = 0; t < nt; ++t) {
        const int p = t & 1;
        if (t + 1 < nt) {
            stage(p ^ 1, t + 1);   // issue next tile (stays in flight)
            asm volatile("s_waitcnt vmcnt(%0)" :: "n"(LPT) : "memory");
        } else {
            asm volatile("s_waitcnt vmcnt(0)" ::: "memory");
        }
        __builtin_amdgcn_s_barrier();   // raw: no implicit drain

        bf16x8 af[MIF][KK], bfr[NJF][KK];
#pragma unroll
        for (int i = 0; i < MIF; i++)
#pragma unroll
            for (int kk = 0; kk < KK; kk++)
                af[i][kk] = *(const bf16x8*)(&As[p][(wm * WM + i * 16 + lr) * BKT + kk * 32 + lk]);
#pragma unroll
        for (int j = 0; j < NJF; j++)
#pragma unroll
            for (int kk = 0; kk < KK; kk++)
                bfr[j][kk] = *(const bf16x8*)(&Bs[p][(wn * WN + j * 16 + lr) * BKT + kk * 32 + lk]);
#pragma unroll
        for (int kk = 0; kk < KK; kk++)
#pragma unroll
            for (int i = 0; i < MIF; i++)
#pragma unroll
                for (int j = 0; j < NJF; j++)
                    acc[i][j] = __builtin_amdgcn_mfma_f32_16x16x32_bf16(af[i][kk], bfr[j][kk], acc[i][j], 0, 0, 0);

        asm volatile("" ::: "memory");
        __builtin_amdgcn_s_barrier();
    }

    const int rq = (lane >> 4) * 4;
#pragma unroll
    for (int j = 0; j < NJF; j++) {
        const int col = n0 + wn * WN + j * 16 + lr;
        const float bv = bias[col];
#pragma unroll
        for (int i = 0; i < MIF; i++) {
#pragma unroll
            for (int r = 0; r < 4; r++) {
                const int row = m0 + wm * WM + i * 16 + rq + r;
                float v = acc[i][j][r] + bv;
                if (MODE == 2) {
                    v = 0.5f * v * (1.0f + erff(v * 0.70710678118654752f));
                }
                Cout[(size_t)row * N + col] = f2bf(v);
            }
        }
    }
}

// ---------------------------------------------------------------------------
// MFMA flash attention. hd=64, D=1024, H=16. Q/K/V bf16 ws [b,l,h*64+d].
// Block: 256 thr = 4 waves, one (b,h), 64 q rows (16/wave). KVBLK=64.
// Reg-prefetch staging; XCD-swizzled block map; DPP row_ror softmax;
// defer-max (T13): skip exp(alpha)+O-rescale when __all(mx-m_i <= 8) —
// P bounded by e^8, safe in f32 accum; first tile never skips.
// Grid MUST be (16, 64).
// ---------------------------------------------------------------------------
__global__ void __launch_bounds__(256) mfma_attn_kernel(
    const ushort_t* __restrict__ Q, const ushort_t* __restrict__ Kt,
    const ushort_t* __restrict__ Vt, const float* __restrict__ mask,
    ushort_t* __restrict__ O, int Lq, int Lk, float scale)
{
    __shared__ __align__(16) ushort_t qs[64][72];
    __shared__ __align__(16) ushort_t ks[64][72];
    __shared__ __align__(16) ushort_t vsT[64][72];   // [d][k ^ swz(d)]
    __shared__ __align__(16) ushort_t ps[4][16][72]; // per-wave P [q][k]

    const int tid = threadIdx.x;
    const int wave = tid >> 6, lane = tid & 63;
    const int quad = lane >> 4, lc = lane & 15;

    const int id = blockIdx.x + (int)gridDim.x * blockIdx.y;  // 0..1023
    const int bh = (id & 7) * 8 + ((id >> 3) >> 4);
    const int qt = (id >> 3) & 15;
    const int b = bh >> 4, h = bh & 15;
    const int q0 = qt * 64;
    const size_t qbase = ((size_t)b * Lq) * 1024 + h * 64;
    const size_t kbase = ((size_t)b * Lk) * 1024 + h * 64;
    const float* maskb = mask ? (mask + (size_t)b * Lk) : nullptr;

#pragma unroll
    for (int r = 0; r < 2; r++) {
        int v = r * 256 + tid;
        int row = v >> 3, c8 = (v & 7) * 8;
        *(uint4*)(&qs[row][c8]) = *(const uint4*)(&Q[qbase + (size_t)(q0 + row) * 1024 + c8]);
    }
    __syncthreads();

    bf16x8 qa0 = *(const bf16x8*)(&qs[wave * 16 + lc][quad * 8]);
    bf16x8 qa1 = *(const bf16x8*)(&qs[wave * 16 + lc][32 + quad * 8]);

    f32x4 o[4];
#pragma unroll
    for (int d = 0; d < 4; d++) o[d] = (f32x4){0.f, 0.f, 0.f, 0.f};
    float m_i[4], l_i[4];
#pragma unroll
    for (int r = 0; r < 4; r++) { m_i[r] = -1e30f; l_i[r] = 0.f; }

    const int sr = tid >> 2;
    const int d0c = (tid & 3) * 16;
    const int vswz = (tid & 3) << 3;
    const int vcol = sr ^ vswz;

    const int nt = Lk >> 6;
    size_t gk = kbase + (size_t)sr * 1024 + d0c;

    uint4 kA = *(const uint4*)(Kt + gk);
    uint4 kB = *(const uint4*)(Kt + gk + 8);
    uint4 vA = *(const uint4*)(Vt + gk);
    uint4 vB = *(const uint4*)(Vt + gk + 8);

    for (int t = 0; t < nt; ++t) {
        const int kt = t << 6;
        __syncthreads();
        *(uint4*)(&ks[sr][d0c])     = kA;
        *(uint4*)(&ks[sr][d0c + 8]) = kB;
        {
            const ushort_t* vp = (const ushort_t*)&vA;
            const ushort_t* wp = (const ushort_t*)&vB;
#pragma unroll
            for (int i = 0; i < 8; i++) vsT[d0c + i][vcol]     = vp[i];
#pragma unroll
            for (int i = 0; i < 8; i++) vsT[d0c + 8 + i][vcol] = wp[i];
        }
        if (t + 1 < nt) {
            gk += 64 * 1024;
            kA = *(const uint4*)(Kt + gk);
            kB = *(const uint4*)(Kt + gk + 8);
            vA = *(const uint4*)(Vt + gk);
            vB = *(const uint4*)(Vt + gk + 8);
        }
        __syncthreads();

        float mk[4];
#pragma unroll
        for (int g = 0; g < 4; g++)
            mk[g] = maskb ? maskb[kt + g * 16 + lc] : 0.f;

        f32x4 s[4];
        __builtin_amdgcn_s_setprio(1);
#pragma unroll
        for (int g = 0; g < 4; g++) {
            bf16x8 k0 = *(const bf16x8*)(&ks[g * 16 + lc][quad * 8]);
            bf16x8 k1 = *(const bf16x8*)(&ks[g * 16 + lc][32 + quad * 8]);
            f32x4 zz = (f32x4){0.f, 0.f, 0.f, 0.f};
            zz = __builtin_amdgcn_mfma_f32_16x16x32_bf16(qa0, k0, zz, 0, 0, 0);
            zz = __builtin_amdgcn_mfma_f32_16x16x32_bf16(qa1, k1, zz, 0, 0, 0);
            s[g] = zz;
        }
        __builtin_amdgcn_s_setprio(0);

        // online softmax; reductions over the 16 lanes of this quad via DPP
        float alpha[4];
        bool need = false;
#pragma unroll
        for (int r = 0; r < 4; r++) {
            float v0 = s[0][r] * scale + mk[0];
            float v1 = s[1][r] * scale + mk[1];
            float v2 = s[2][r] * scale + mk[2];
            float v3 = s[3][r] * scale + mk[3];
            float mx = fmaxf(fmaxf(v0, v1), fmaxf(v2, v3));
            mx = fmaxf(mx, ror16f<1>(mx));
            mx = fmaxf(mx, ror16f<2>(mx));
            mx = fmaxf(mx, ror16f<4>(mx));
            mx = fmaxf(mx, ror16f<8>(mx));
            float mnew;
            if (__all(mx - m_i[r] <= 8.0f)) {      // defer-max (T13)
                alpha[r] = 1.0f;
                mnew = m_i[r];
            } else {
                mnew = fmaxf(m_i[r], mx);
                alpha[r] = __expf(m_i[r] - mnew);
                m_i[r] = mnew;
                need = true;
            }
            float p0 = __expf(v0 - mnew);
            float p1 = __expf(v1 - mnew);
            float p2 = __expf(v2 - mnew);
            float p3 = __expf(v3 - mnew);
            ps[wave][quad * 4 + r][lc]      = f2bf_hw(p0);
            ps[wave][quad * 4 + r][16 + lc] = f2bf_hw(p1);
            ps[wave][quad * 4 + r][32 + lc] = f2bf_hw(p2);
            ps[wave][quad * 4 + r][48 + lc] = f2bf_hw(p3);
            float psum = (p0 + p1) + (p2 + p3);
            psum += ror16f<1>(psum);
            psum += ror16f<2>(psum);
            psum += ror16f<4>(psum);
            psum += ror16f<8>(psum);
            l_i[r] = l_i[r] * alpha[r] + psum;
        }
        if (need) {   // wave-uniform (__all-derived)
#pragma unroll
            for (int d = 0; d < 4; d++)
#pragma unroll
                for (int r = 0; r < 4; r++) o[d][r] *= alpha[r];
        }

        __builtin_amdgcn_s_setprio(1);
#pragma unroll
        for (int kk = 0; kk < 2; kk++) {
            bf16x8 pa = *(const bf16x8*)(&ps[wave][lc][kk * 32 + quad * 8]);
#pragma unroll
            for (int d = 0; d < 4; d++) {
                int dr = d * 16 + lc;
                bf16x8 vb = *(const bf16x8*)(&vsT[dr][(kk * 32 + quad * 8) ^ (d << 3)]);
                o[d] = __builtin_amdgcn_mfma_f32_16x16x32_bf16(pa, vb, o[d], 0, 0, 0);
            }
        }
        __builtin_amdgcn_s_setprio(0);
    }

#pragma unroll
    for (int d = 0; d < 4; d++) {
#pragma unroll
        for (int r = 0; r < 4; r++) {
            float val = o[d][r] / l_i[r];
            O[qbase + (size_t)(q0 + wave * 16 + quad * 4 + r) * 1024 + d * 16 + lc] = f2bf_hw(val);
        }
    }
}

// ---------------------------------------------------------------------------
// Fused residual + LayerNorm (rows of 1024). Unchanged.
// ---------------------------------------------------------------------------
template <bool RES_F32, bool OUT_F32>
__global__ void __launch_bounds__(256) ln_kernel(
    const ushort_t* __restrict__ Hbuf, const void* __restrict__ Res,
    const float* __restrict__ gamma, const float* __restrict__ beta,
    void* __restrict__ Out)
{
    const int row = blockIdx.x;
    const int tid = threadIdx.x;
    const size_t base = (size_t)row * 1024 + tid * 4;

    uint2 hh = *(const uint2*)(Hbuf + base);
    float v[4];
    v[0] = bf2f(hh.x & 0xffffu);
    v[1] = bf2f(hh.x >> 16);
    v[2] = bf2f(hh.y & 0xffffu);
    v[3] = bf2f(hh.y >> 16);
    if (RES_F32) {
        float4 rv = *(const float4*)((const float*)Res + base);
        v[0] += rv.x; v[1] += rv.y; v[2] += rv.z; v[3] += rv.w;
    } else {
        uint2 rr = *(const uint2*)((const ushort_t*)Res + base);
        v[0] += bf2f(rr.x & 0xffffu);
        v[1] += bf2f(rr.x >> 16);
        v[2] += bf2f(rr.y & 0xffffu);
        v[3] += bf2f(rr.y >> 16);
    }

    float s = v[0] + v[1] + v[2] + v[3];
    float s2 = v[0]*v[0] + v[1]*v[1] + v[2]*v[2] + v[3]*v[3];
#pragma unroll
    for (int o = 1; o < 64; o <<= 1) {
        s += __shfl_xor(s, o, 64);
        s2 += __shfl_xor(s2, o, 64);
    }
    __shared__ float red[8];
    const int wv = tid >> 6, ln_ = tid & 63;
    if (ln_ == 0) { red[wv] = s; red[wv + 4] = s2; }
    __syncthreads();
    s = red[0] + red[1] + red[2] + red[3];
    s2 = red[4] + red[5] + red[6] + red[7];
    const float mu = s * (1.0f / 1024.0f);
    const float var = s2 * (1.0f / 1024.0f) - mu * mu;
    const float rstd = rsqrtf(var + 1e-5f);

    float4 gv = *(const float4*)(&gamma[tid * 4]);
    float4 bv = *(const float4*)(&beta[tid * 4]);
    float o0 = (v[0] - mu) * rstd * gv.x + bv.x;
    float o1 = (v[1] - mu) * rstd * gv.y + bv.y;
    float o2 = (v[2] - mu) * rstd * gv.z + bv.z;
    float o3 = (v[3] - mu) * rstd * gv.w + bv.w;

    if (OUT_F32) {
        float4 of = {o0, o1, o2, o3};
        *(float4*)((float*)Out + base) = of;
    } else {
        ushort_t ob[4] = {f2bf(o0), f2bf(o1), f2bf(o2), f2bf(o3)};
        *(uint2*)((ushort_t*)Out + base) = *(uint2*)ob;
    }
}

// ---------------------------------------------------------------------------
// Launch. ws layout (72 MB total, phase-local aliasing):
//   0-8   Bq            (FFN phase: WtG = fi^T / fo^T, Bq dead)
//   8-24  Bk            (FFN phase: Bi [8,40))
//   24-40 Bv
//   40-56 Xctx early -> Ba[40,48) + Bh[48,56)
//   56-64 Bx1           (cross phase, pre-LN: WtA/WtB/WtC @56/58/60)
//   64-72 Xin early -> (self phase: WtD/WtE/WtF @64/66/68) -> Bx2
// ---------------------------------------------------------------------------
extern "C" void kernel_launch(void* const* d_in, const int* in_sizes, int n_in,
                              void* d_out, int out_size, void* d_ws, size_t ws_size,
                              hipStream_t stream)
{
    const float* input = (const float*)d_in[0];
    const float* ctx   = (const float*)d_in[1];
    const float* mask  = (const float*)d_in[2];
    const float* cq_w = (const float*)d_in[3],  *cq_b = (const float*)d_in[4];
    const float* ck_w = (const float*)d_in[5],  *ck_b = (const float*)d_in[6];
    const float* cv_w = (const float*)d_in[7],  *cv_b = (const float*)d_in[8];
    const float* co_w = (const float*)d_in[9],  *co_b = (const float*)d_in[10];
    const float* co_g = (const float*)d_in[11], *co_be = (const float*)d_in[12];
    const float* sq_w = (const float*)d_in[13], *sq_b = (const float*)d_in[14];
    const float* sk_w = (const float*)d_in[15], *sk_b = (const float*)d_in[16];
    const float* sv_w = (const float*)d_in[17], *sv_b = (const float*)d_in[18];
    const float* so_w = (const float*)d_in[19], *so_b = (const float*)d_in[20];
    const float* so_g = (const float*)d_in[21], *so_be = (const float*)d_in[22];
    const float* fi_w = (const float*)d_in[23], *fi_b = (const float*)d_in[24];
    const float* fo_w = (const float*)d_in[25], *fo_b = (const float*)d_in[26];
    const float* fo_g = (const float*)d_in[27], *fo_be = (const float*)d_in[28];

    char* p = (char*)d_ws;
    const size_t MB = 1024 * 1024;
    ushort_t* Bq   = (ushort_t*)(p + 0 * MB);
    ushort_t* Bk   = (ushort_t*)(p + 8 * MB);
    ushort_t* Bv   = (ushort_t*)(p + 24 * MB);
    ushort_t* Ba   = (ushort_t*)(p + 40 * MB);
    ushort_t* Bh   = (ushort_t*)(p + 48 * MB);
    ushort_t* Bx1  = (ushort_t*)(p + 56 * MB);
    ushort_t* Bx2  = (ushort_t*)(p + 64 * MB);
    ushort_t* Bi   = Bk;                       // [8,40) during FFN
    ushort_t* Xctx = Ba;                       // [40,56) early only
    ushort_t* Xin  = Bx2;                      // [64,72) early only
    ushort_t* WtA  = (ushort_t*)(p + 56 * MB); // cross-phase W^T scratch
    ushort_t* WtB  = (ushort_t*)(p + 58 * MB);
    ushort_t* WtC  = (ushort_t*)(p + 60 * MB);
    ushort_t* WtD  = (ushort_t*)(p + 64 * MB); // self-phase W^T scratch
    ushort_t* WtE  = (ushort_t*)(p + 66 * MB);
    ushort_t* WtF  = (ushort_t*)(p + 68 * MB);
    ushort_t* WtG  = (ushort_t*)(p + 0 * MB);  // FFN-phase W^T scratch (8 MB)

    const float scale = 0.125f;
    dim3 blk(256);

    // ---- activation conversions ----
    cvt_bf16_kernel<<<2048, blk, 0, stream>>>(input, Xin, 524288);
    cvt_bf16_kernel<<<4096, blk, 0, stream>>>(ctx, Xctx, 1048576);

    // ---- cross attention ----
    wconv_kernel<<<dim3(32, 32), blk, 0, stream>>>(cq_w, WtA, 1024, 1024);
    wconv_kernel<<<dim3(32, 32), blk, 0, stream>>>(ck_w, WtB, 1024, 1024);
    wconv_kernel<<<dim3(32, 32), blk, 0, stream>>>(cv_w, WtC, 1024, 1024);
    // merged cq (Xin, M=4096) + ck/cv (Xctx, M=8192) in one z=3 launch
    gemm_bt_kernel<0, 128, 64, 64><<<dim3(16, 64, 3), blk, 0, stream>>>(
        Xin, Xctx, 4096, 8192, WtA, WtB, WtC, cq_b, ck_b, cv_b,
        Bq, Bk, Bv, 1024, 1024);
    mfma_attn_kernel<<<dim3(16, 64), blk, 0, stream>>>(Bq, Bk, Bv, mask, Ba, 1024, 2048, scale);
    wconv_kernel<<<dim3(32, 32), blk, 0, stream>>>(co_w, WtA, 1024, 1024);
    gemm_bt_kernel<0, 128, 64, 64><<<dim3(16, 32, 1), blk, 0, stream>>>(
        Ba, Ba, 4096, 4096, WtA, WtA, WtA, co_b, co_b, co_b,
        Bh, Bh, Bh, 1024, 1024);
    ln_kernel<true, false><<<dim3(4096), blk, 0, stream>>>(Bh, input, co_g, co_be, Bx1);

    // ---- self attention ----
    wconv_kernel<<<dim3(32, 32), blk, 0, stream>>>(sq_w, WtD, 1024, 1024);
    wconv_kernel<<<dim3(32, 32), blk, 0, stream>>>(sk_w, WtE, 1024, 1024);
    wconv_kernel<<<dim3(32, 32), blk, 0, stream>>>(sv_w, WtF, 1024, 1024);
    gemm_bt_kernel<0, 128, 64, 64><<<dim3(16, 32, 3), blk, 0, stream>>>(
        Bx1, Bx1, 4096, 4096, WtD, WtE, WtF, sq_b, sk_b, sv_b,
        Bq, Bk, Bv, 1024, 1024);
    mfma_attn_kernel<<<dim3(16, 64), blk, 0, stream>>>(Bq, Bk, Bv, nullptr, Ba, 1024, 1024, scale);
    wconv_kernel<<<dim3(32, 32), blk, 0, stream>>>(so_w, WtD, 1024, 1024);
    gemm_bt_kernel<0, 128, 64, 64><<<dim3(16, 32, 1), blk, 0, stream>>>(
        Ba, Ba, 4096, 4096, WtD, WtD, WtD, so_b, so_b, so_b,
        Bh, Bh, Bh, 1024, 1024);
    ln_kernel<false, false><<<dim3(4096), blk, 0, stream>>>(Bh, Bx1, so_g, so_be, Bx2);

    // ---- FFN ----
    wconv_kernel<<<dim3(32, 128), blk, 0, stream>>>(fi_w, WtG, 1024, 4096);
    gemm_bt_kernel<2, 128, 128, 32><<<dim3(32, 32, 1), blk, 0, stream>>>(
        Bx2, Bx2, 4096, 4096, WtG, WtG, WtG, fi_b, fi_b, fi_b,
        Bi, Bi, Bi, 4096, 1024);
    wconv_kernel<<<dim3(128, 32), blk, 0, stream>>>(fo_w, WtG, 4096, 1024);
    gemm_bt_kernel<0, 128, 64, 64><<<dim3(16, 32, 1), blk, 0, stream>>>(
        Bi, Bi, 4096, 4096, WtG, WtG, WtG, fo_b, fo_b, fo_b,
        Bh, Bh, Bh, 1024, 4096);
    ln_kernel<false, true><<<dim3(4096), blk, 0, stream>>>(Bh, Bx2, fo_g, fo_be, (float*)d_out);
}

// Round 17
// 655.674 us; speedup vs baseline: 1.0666x; 1.0152x over previous
//
#include <hip/hip_runtime.h>
#include <math.h>

typedef unsigned short ushort_t;
typedef __bf16 bf16x8 __attribute__((ext_vector_type(8)));
typedef float f32x4 __attribute__((ext_vector_type(4)));

#define LOG2E 1.44269504088896340736f

__device__ __forceinline__ float bf2f(unsigned int u) {
    union { unsigned int i; float f; } v; v.i = u << 16; return v.f;
}
__device__ __forceinline__ ushort_t f2bf(float f) {
    union { float f; unsigned int i; } v; v.f = f;
    unsigned int u = v.i;
    unsigned int r = u + 0x7fffu + ((u >> 16) & 1u);
    return (ushort_t)(r >> 16);
}
// HW RTNE bf16 cast (single v_cvt; bit-identical to f2bf for finite inputs)
__device__ __forceinline__ ushort_t f2bf_hw(float f) {
    union { __bf16 h; ushort_t u; } v; v.h = (__bf16)f; return v.u;
}
// native 2^x (single v_exp_f32, no pre-multiply)
__device__ __forceinline__ float exp2f_hw(float x) {
    float r; asm("v_exp_f32 %0, %1" : "=v"(r) : "v"(x)); return r;
}

// DPP row-rotate (16-lane rows) for cross-lane reduce without LDS pipe.
template <int N>
__device__ __forceinline__ float ror16f(float x) {
    union { float f; int i; } u; u.f = x;
    u.i = __builtin_amdgcn_mov_dpp(u.i, 0x120 + N, 0xF, 0xF, true);
    return u.f;
}

// async global->LDS, 16B per lane. Dest must be linear: base + lane*16.
__device__ __forceinline__ void gload16(const ushort_t* g, ushort_t* l) {
    __builtin_amdgcn_global_load_lds(
        (__attribute__((address_space(1))) void*)g,
        (__attribute__((address_space(3))) void*)l, 16, 0, 0);
}

// ---------------------------------------------------------------------------
// fp32 -> bf16 elementwise (activations). 8 elems/thread.
// ---------------------------------------------------------------------------
__global__ void __launch_bounds__(256) cvt_bf16_kernel(
    const float* __restrict__ in, ushort_t* __restrict__ out, int n8)
{
    int i = blockIdx.x * 256 + threadIdx.x;
    if (i >= n8) return;
    size_t off = (size_t)i * 8;
    float4 a = *(const float4*)(in + off);
    float4 b = *(const float4*)(in + off + 4);
    ushort_t o[8] = {f2bf(a.x), f2bf(a.y), f2bf(a.z), f2bf(a.w),
                     f2bf(b.x), f2bf(b.y), f2bf(b.z), f2bf(b.w)};
    *(uint4*)(out + off) = *(const uint4*)o;
}

// ---------------------------------------------------------------------------
// W [K,N] fp32 -> Wt [N,K] bf16 (transpose+convert), 32x32 LDS tiles.
// Single-W form (FFN) and z=4 batched form (QKV/proj weight groups).
// ---------------------------------------------------------------------------
__device__ __forceinline__ void wconv_body(
    const float* __restrict__ W, ushort_t* __restrict__ Wt, int K, int N,
    int bx, int by)
{
    __shared__ float tile[32][33];
    const int t = threadIdx.x;
    const int k0 = bx * 32, n0 = by * 32;
    const int r = t >> 3, c4 = (t & 7) * 4;
    float4 d = *(const float4*)(&W[(size_t)(k0 + r) * N + n0 + c4]);
    tile[r][c4 + 0] = d.x; tile[r][c4 + 1] = d.y;
    tile[r][c4 + 2] = d.z; tile[r][c4 + 3] = d.w;
    __syncthreads();
    ushort_t o[4] = { f2bf(tile[c4 + 0][r]), f2bf(tile[c4 + 1][r]),
                      f2bf(tile[c4 + 2][r]), f2bf(tile[c4 + 3][r]) };
    *(uint2*)(&Wt[(size_t)(n0 + r) * K + k0 + c4]) = *(const uint2*)o;
}

__global__ void __launch_bounds__(256) wconv_kernel(
    const float* __restrict__ W, ushort_t* __restrict__ Wt, int K, int N)
{
    wconv_body(W, Wt, K, N, blockIdx.x, blockIdx.y);
}

__global__ void __launch_bounds__(256) wconv4_kernel(
    const float* __restrict__ W0, const float* __restrict__ W1,
    const float* __restrict__ W2, const float* __restrict__ W3,
    ushort_t* __restrict__ T0, ushort_t* __restrict__ T1,
    ushort_t* __restrict__ T2, ushort_t* __restrict__ T3,
    int K, int N)
{
    const int z = blockIdx.z;
    const float* W = (z == 0) ? W0 : (z == 1) ? W1 : (z == 2) ? W2 : W3;
    ushort_t* Wt = (z == 0) ? T0 : (z == 1) ? T1 : (z == 2) ? T2 : T3;
    wconv_body(W, Wt, K, N, blockIdx.x, blockIdx.y);
}

// ---------------------------------------------------------------------------
// GEMM (B^T form): C[M,N] = A[M,K](bf16) @ Bt[N,K](bf16)^T + bias.
// BMT=128, BNT in {64,128}, BKT in {32,64}, 4 waves (2x2),
// mfma_f32_16x16x32_bf16. T4 counted-vmcnt schedule with RAW s_barrier:
//   issue stage(t+1) -> vmcnt(LPT) [tile-t loads retired, FIFO per m135]
//   -> raw barrier -> ds_read+MFMA -> raw barrier.
// Per-z (A, M) batches independent GEMMs into one launch. Padding blocks
// (m0 >= Mz) exit before any barrier (whole block exits together).
// blockIdx.z selects (A,M,W,bias,C). MODE 2 adds exact GELU.
// Unchanged from R14 (best measured).
// ---------------------------------------------------------------------------
template <int MODE, int BMT, int BNT, int BKT>
__global__ void __launch_bounds__(256) gemm_bt_kernel(
    const ushort_t* __restrict__ A0, const ushort_t* __restrict__ A1,
    int M0, int M1,
    const ushort_t* __restrict__ B0, const ushort_t* __restrict__ B1,
    const ushort_t* __restrict__ B2,
    const float* __restrict__ bias0, const float* __restrict__ bias1,
    const float* __restrict__ bias2,
    ushort_t* __restrict__ C0, ushort_t* __restrict__ C1,
    ushort_t* __restrict__ C2,
    int N, int K)
{
    __shared__ __align__(16) ushort_t As[2][BMT * BKT];
    __shared__ __align__(16) ushort_t Bs[2][BNT * BKT];

    constexpr int WM = BMT / 2;       // per-wave M extent
    constexpr int MIF = WM / 16;      // M frags per wave
    constexpr int WN = BNT / 2;       // per-wave N extent
    constexpr int NJF = WN / 16;      // N frags per wave
    constexpr int KK = BKT / 32;      // K sub-steps per tile
    constexpr int CPR = BKT / 8;      // 16B chunks per row
    constexpr int PA = BMT * BKT / 2048;  // staging passes for A
    constexpr int PB = BNT * BKT / 2048;  // staging passes for B
    constexpr int LPT = PA + PB;          // loads per tile per thread

    const int z = blockIdx.z;
    const ushort_t* A = (z == 0) ? A0 : A1;
    const int Mz = (z == 0) ? M0 : M1;
    const ushort_t* Bt = (z == 0) ? B0 : ((z == 1) ? B1 : B2);
    const float* bias = (z == 0) ? bias0 : ((z == 1) ? bias1 : bias2);
    ushort_t* Cout = (z == 0) ? C0 : ((z == 1) ? C1 : C2);

    const int tid = threadIdx.x;
    const int m0 = blockIdx.y * BMT, n0 = blockIdx.x * BNT;
    if (m0 >= Mz) return;   // merged-launch padding blocks
    const int wave = tid >> 6, lane = tid & 63;
    const int wm = wave >> 1, wn = wave & 1;
    const int lr = lane & 15;
    const int lk = (lane >> 4) * 8;

    const ushort_t* Ab = A + (size_t)m0 * K;
    const ushort_t* Bb = Bt + (size_t)n0 * K;

    f32x4 acc[MIF][NJF];
#pragma unroll
    for (int i = 0; i < MIF; i++)
#pragma unroll
        for (int j = 0; j < NJF; j++) acc[i][j] = (f32x4){0.f, 0.f, 0.f, 0.f};

    const int nt = K / BKT;

    auto stage = [&](int buf, int t) {
#pragma unroll
        for (int p = 0; p < PA; p++) {
            int v = p * 256 + tid;
            int row = v / CPR, c = v % CPR;
            gload16(Ab + (size_t)row * K + (size_t)t * BKT + c * 8,
                    &As[buf][v * 8]);
        }
#pragma unroll
        for (int p = 0; p < PB; p++) {
            int v = p * 256 + tid;
            int row = v / CPR, c = v % CPR;
            gload16(Bb + (size_t)row * K + (size_t)t * BKT + c * 8,
                    &Bs[buf][v * 8]);
        }
    };

    // prologue: tile 0 into buffer 0 (loads left in flight; counted below)
    stage(0, 0);

    for (int t = 0; t < nt; ++t) {
        const int p = t & 1;
        if (t + 1 < nt) {
            stage(p ^ 1, t + 1);   // issue next tile (stays in flight)
            asm volatile("s_waitcnt vmcnt(%0)" :: "n"(LPT) : "memory");
        } else {
            asm volatile("s_waitcnt vmcnt(0)" ::: "memory");
        }
        __builtin_amdgcn_s_barrier();   // raw: no implicit drain

        bf16x8 af[MIF][KK], bfr[NJF][KK];
#pragma unroll
        for (int i = 0; i < MIF; i++)
#pragma unroll
            for (int kk = 0; kk < KK; kk++)
                af[i][kk] = *(const bf16x8*)(&As[p][(wm * WM + i * 16 + lr) * BKT + kk * 32 + lk]);
#pragma unroll
        for (int j = 0; j < NJF; j++)
#pragma unroll
            for (int kk = 0; kk < KK; kk++)
                bfr[j][kk] = *(const bf16x8*)(&Bs[p][(wn * WN + j * 16 + lr) * BKT + kk * 32 + lk]);
#pragma unroll
        for (int kk = 0; kk < KK; kk++)
#pragma unroll
            for (int i = 0; i < MIF; i++)
#pragma unroll
                for (int j = 0; j < NJF; j++)
                    acc[i][j] = __builtin_amdgcn_mfma_f32_16x16x32_bf16(af[i][kk], bfr[j][kk], acc[i][j], 0, 0, 0);

        asm volatile("" ::: "memory");
        __builtin_amdgcn_s_barrier();
    }

    const int rq = (lane >> 4) * 4;
#pragma unroll
    for (int j = 0; j < NJF; j++) {
        const int col = n0 + wn * WN + j * 16 + lr;
        const float bv = bias[col];
#pragma unroll
        for (int i = 0; i < MIF; i++) {
#pragma unroll
            for (int r = 0; r < 4; r++) {
                const int row = m0 + wm * WM + i * 16 + rq + r;
                float v = acc[i][j][r] + bv;
                if (MODE == 2) {
                    v = 0.5f * v * (1.0f + erff(v * 0.70710678118654752f));
                }
                Cout[(size_t)row * N + col] = f2bf(v);
            }
        }
    }
}

// ---------------------------------------------------------------------------
// MFMA flash attention. hd=64, D=1024, H=16. Q/K/V bf16 ws [b,l,h*64+d].
// Block: 256 thr = 4 waves, one (b,h), 64 q rows (16/wave). KVBLK=64.
// Reg-prefetch staging; XCD-swizzled block map; DPP row_ror softmax.
// EXP2-DOMAIN softmax: scale is pre-multiplied by log2(e) on host; mask is
// scaled by LOG2E in-kernel (4 muls/tile vs 16); exp -> native v_exp_f32.
// Mathematically identical (max commutes with positive scaling).
// defer-max threshold 8 (e-domain) -> 11.5 (base-2). Grid MUST be (16, 64).
// ---------------------------------------------------------------------------
__global__ void __launch_bounds__(256) mfma_attn_kernel(
    const ushort_t* __restrict__ Q, const ushort_t* __restrict__ Kt,
    const ushort_t* __restrict__ Vt, const float* __restrict__ mask,
    ushort_t* __restrict__ O, int Lq, int Lk, float scale)
{
    __shared__ __align__(16) ushort_t qs[64][72];
    __shared__ __align__(16) ushort_t ks[64][72];
    __shared__ __align__(16) ushort_t vsT[64][72];   // [d][k ^ swz(d)]
    __shared__ __align__(16) ushort_t ps[4][16][72]; // per-wave P [q][k]

    const int tid = threadIdx.x;
    const int wave = tid >> 6, lane = tid & 63;
    const int quad = lane >> 4, lc = lane & 15;

    const int id = blockIdx.x + (int)gridDim.x * blockIdx.y;  // 0..1023
    const int bh = (id & 7) * 8 + ((id >> 3) >> 4);
    const int qt = (id >> 3) & 15;
    const int b = bh >> 4, h = bh & 15;
    const int q0 = qt * 64;
    const size_t qbase = ((size_t)b * Lq) * 1024 + h * 64;
    const size_t kbase = ((size_t)b * Lk) * 1024 + h * 64;
    const float* maskb = mask ? (mask + (size_t)b * Lk) : nullptr;

#pragma unroll
    for (int r = 0; r < 2; r++) {
        int v = r * 256 + tid;
        int row = v >> 3, c8 = (v & 7) * 8;
        *(uint4*)(&qs[row][c8]) = *(const uint4*)(&Q[qbase + (size_t)(q0 + row) * 1024 + c8]);
    }
    __syncthreads();

    bf16x8 qa0 = *(const bf16x8*)(&qs[wave * 16 + lc][quad * 8]);
    bf16x8 qa1 = *(const bf16x8*)(&qs[wave * 16 + lc][32 + quad * 8]);

    f32x4 o[4];
#pragma unroll
    for (int d = 0; d < 4; d++) o[d] = (f32x4){0.f, 0.f, 0.f, 0.f};
    float m_i[4], l_i[4];
#pragma unroll
    for (int r = 0; r < 4; r++) { m_i[r] = -1e30f; l_i[r] = 0.f; }

    const int sr = tid >> 2;
    const int d0c = (tid & 3) * 16;
    const int vswz = (tid & 3) << 3;
    const int vcol = sr ^ vswz;

    const int nt = Lk >> 6;
    size_t gk = kbase + (size_t)sr * 1024 + d0c;

    uint4 kA = *(const uint4*)(Kt + gk);
    uint4 kB = *(const uint4*)(Kt + gk + 8);
    uint4 vA = *(const uint4*)(Vt + gk);
    uint4 vB = *(const uint4*)(Vt + gk + 8);

    for (int t = 0; t < nt; ++t) {
        const int kt = t << 6;
        __syncthreads();
        *(uint4*)(&ks[sr][d0c])     = kA;
        *(uint4*)(&ks[sr][d0c + 8]) = kB;
        {
            const ushort_t* vp = (const ushort_t*)&vA;
            const ushort_t* wp = (const ushort_t*)&vB;
#pragma unroll
            for (int i = 0; i < 8; i++) vsT[d0c + i][vcol]     = vp[i];
#pragma unroll
            for (int i = 0; i < 8; i++) vsT[d0c + 8 + i][vcol] = wp[i];
        }
        if (t + 1 < nt) {
            gk += 64 * 1024;
            kA = *(const uint4*)(Kt + gk);
            kB = *(const uint4*)(Kt + gk + 8);
            vA = *(const uint4*)(Vt + gk);
            vB = *(const uint4*)(Vt + gk + 8);
        }
        __syncthreads();

        float mk[4];
#pragma unroll
        for (int g = 0; g < 4; g++)
            mk[g] = maskb ? maskb[kt + g * 16 + lc] * LOG2E : 0.f;

        f32x4 s[4];
        __builtin_amdgcn_s_setprio(1);
#pragma unroll
        for (int g = 0; g < 4; g++) {
            bf16x8 k0 = *(const bf16x8*)(&ks[g * 16 + lc][quad * 8]);
            bf16x8 k1 = *(const bf16x8*)(&ks[g * 16 + lc][32 + quad * 8]);
            f32x4 zz = (f32x4){0.f, 0.f, 0.f, 0.f};
            zz = __builtin_amdgcn_mfma_f32_16x16x32_bf16(qa0, k0, zz, 0, 0, 0);
            zz = __builtin_amdgcn_mfma_f32_16x16x32_bf16(qa1, k1, zz, 0, 0, 0);
            s[g] = zz;
        }
        __builtin_amdgcn_s_setprio(0);

        // online softmax in base-2; quad-row DPP reductions
        float alpha[4];
        bool need = false;
#pragma unroll
        for (int r = 0; r < 4; r++) {
            float v0 = s[0][r] * scale + mk[0];
            float v1 = s[1][r] * scale + mk[1];
            float v2 = s[2][r] * scale + mk[2];
            float v3 = s[3][r] * scale + mk[3];
            float mx = fmaxf(fmaxf(v0, v1), fmaxf(v2, v3));
            mx = fmaxf(mx, ror16f<1>(mx));
            mx = fmaxf(mx, ror16f<2>(mx));
            mx = fmaxf(mx, ror16f<4>(mx));
            mx = fmaxf(mx, ror16f<8>(mx));
            float mnew;
            if (__all(mx - m_i[r] <= 11.5f)) {     // defer-max (base-2)
                alpha[r] = 1.0f;
                mnew = m_i[r];
            } else {
                mnew = fmaxf(m_i[r], mx);
                alpha[r] = exp2f_hw(m_i[r] - mnew);
                m_i[r] = mnew;
                need = true;
            }
            float p0 = exp2f_hw(v0 - mnew);
            float p1 = exp2f_hw(v1 - mnew);
            float p2 = exp2f_hw(v2 - mnew);
            float p3 = exp2f_hw(v3 - mnew);
            ps[wave][quad * 4 + r][lc]      = f2bf_hw(p0);
            ps[wave][quad * 4 + r][16 + lc] = f2bf_hw(p1);
            ps[wave][quad * 4 + r][32 + lc] = f2bf_hw(p2);
            ps[wave][quad * 4 + r][48 + lc] = f2bf_hw(p3);
            float psum = (p0 + p1) + (p2 + p3);
            psum += ror16f<1>(psum);
            psum += ror16f<2>(psum);
            psum += ror16f<4>(psum);
            psum += ror16f<8>(psum);
            l_i[r] = l_i[r] * alpha[r] + psum;
        }
        if (need) {   // wave-uniform (__all-derived)
#pragma unroll
            for (int d = 0; d < 4; d++)
#pragma unroll
                for (int r = 0; r < 4; r++) o[d][r] *= alpha[r];
        }

        __builtin_amdgcn_s_setprio(1);
#pragma unroll
        for (int kk = 0; kk < 2; kk++) {
            bf16x8 pa = *(const bf16x8*)(&ps[wave][lc][kk * 32 + quad * 8]);
#pragma unroll
            for (int d = 0; d < 4; d++) {
                int dr = d * 16 + lc;
                bf16x8 vb = *(const bf16x8*)(&vsT[dr][(kk * 32 + quad * 8) ^ (d << 3)]);
                o[d] = __builtin_amdgcn_mfma_f32_16x16x32_bf16(pa, vb, o[d], 0, 0, 0);
            }
        }
        __builtin_amdgcn_s_setprio(0);
    }

#pragma unroll
    for (int d = 0; d < 4; d++) {
#pragma unroll
        for (int r = 0; r < 4; r++) {
            float val = o[d][r] / l_i[r];
            O[qbase + (size_t)(q0 + wave * 16 + quad * 4 + r) * 1024 + d * 16 + lc] = f2bf_hw(val);
        }
    }
}

// ---------------------------------------------------------------------------
// Fused residual + LayerNorm (rows of 1024). Unchanged.
// ---------------------------------------------------------------------------
template <bool RES_F32, bool OUT_F32>
__global__ void __launch_bounds__(256) ln_kernel(
    const ushort_t* __restrict__ Hbuf, const void* __restrict__ Res,
    const float* __restrict__ gamma, const float* __restrict__ beta,
    void* __restrict__ Out)
{
    const int row = blockIdx.x;
    const int tid = threadIdx.x;
    const size_t base = (size_t)row * 1024 + tid * 4;

    uint2 hh = *(const uint2*)(Hbuf + base);
    float v[4];
    v[0] = bf2f(hh.x & 0xffffu);
    v[1] = bf2f(hh.x >> 16);
    v[2] = bf2f(hh.y & 0xffffu);
    v[3] = bf2f(hh.y >> 16);
    if (RES_F32) {
        float4 rv = *(const float4*)((const float*)Res + base);
        v[0] += rv.x; v[1] += rv.y; v[2] += rv.z; v[3] += rv.w;
    } else {
        uint2 rr = *(const uint2*)((const ushort_t*)Res + base);
        v[0] += bf2f(rr.x & 0xffffu);
        v[1] += bf2f(rr.x >> 16);
        v[2] += bf2f(rr.y & 0xffffu);
        v[3] += bf2f(rr.y >> 16);
    }

    float s = v[0] + v[1] + v[2] + v[3];
    float s2 = v[0]*v[0] + v[1]*v[1] + v[2]*v[2] + v[3]*v[3];
#pragma unroll
    for (int o = 1; o < 64; o <<= 1) {
        s += __shfl_xor(s, o, 64);
        s2 += __shfl_xor(s2, o, 64);
    }
    __shared__ float red[8];
    const int wv = tid >> 6, ln_ = tid & 63;
    if (ln_ == 0) { red[wv] = s; red[wv + 4] = s2; }
    __syncthreads();
    s = red[0] + red[1] + red[2] + red[3];
    s2 = red[4] + red[5] + red[6] + red[7];
    const float mu = s * (1.0f / 1024.0f);
    const float var = s2 * (1.0f / 1024.0f) - mu * mu;
    const float rstd = rsqrtf(var + 1e-5f);

    float4 gv = *(const float4*)(&gamma[tid * 4]);
    float4 bv = *(const float4*)(&beta[tid * 4]);
    float o0 = (v[0] - mu) * rstd * gv.x + bv.x;
    float o1 = (v[1] - mu) * rstd * gv.y + bv.y;
    float o2 = (v[2] - mu) * rstd * gv.z + bv.z;
    float o3 = (v[3] - mu) * rstd * gv.w + bv.w;

    if (OUT_F32) {
        float4 of = {o0, o1, o2, o3};
        *(float4*)((float*)Out + base) = of;
    } else {
        ushort_t ob[4] = {f2bf(o0), f2bf(o1), f2bf(o2), f2bf(o3)};
        *(uint2*)((ushort_t*)Out + base) = *(uint2*)ob;
    }
}

// ---------------------------------------------------------------------------
// Launch. ws layout (72 MB total, phase-local aliasing):
//   0-8   Bq            (FFN phase: WtG = fi^T / fo^T, Bq dead)
//   8-24  Bk            (FFN phase: Bi [8,40))
//   24-40 Bv
//   40-56 Xctx early -> Ba[40,48) + Bh[48,56)
//   56-64 Bx1           (cross phase, pre-LN: WtA/WtB/WtC/WtCO @56/58/60/62)
//   64-72 Xin early -> (self phase: WtD/WtE/WtF/WtH @64/66/68/70) -> Bx2
// ---------------------------------------------------------------------------
extern "C" void kernel_launch(void* const* d_in, const int* in_sizes, int n_in,
                              void* d_out, int out_size, void* d_ws, size_t ws_size,
                              hipStream_t stream)
{
    const float* input = (const float*)d_in[0];
    const float* ctx   = (const float*)d_in[1];
    const float* mask  = (const float*)d_in[2];
    const float* cq_w = (const float*)d_in[3],  *cq_b = (const float*)d_in[4];
    const float* ck_w = (const float*)d_in[5],  *ck_b = (const float*)d_in[6];
    const float* cv_w = (const float*)d_in[7],  *cv_b = (const float*)d_in[8];
    const float* co_w = (const float*)d_in[9],  *co_b = (const float*)d_in[10];
    const float* co_g = (const float*)d_in[11], *co_be = (const float*)d_in[12];
    const float* sq_w = (const float*)d_in[13], *sq_b = (const float*)d_in[14];
    const float* sk_w = (const float*)d_in[15], *sk_b = (const float*)d_in[16];
    const float* sv_w = (const float*)d_in[17], *sv_b = (const float*)d_in[18];
    const float* so_w = (const float*)d_in[19], *so_b = (const float*)d_in[20];
    const float* so_g = (const float*)d_in[21], *so_be = (const float*)d_in[22];
    const float* fi_w = (const float*)d_in[23], *fi_b = (const float*)d_in[24];
    const float* fo_w = (const float*)d_in[25], *fo_b = (const float*)d_in[26];
    const float* fo_g = (const float*)d_in[27], *fo_be = (const float*)d_in[28];

    char* p = (char*)d_ws;
    const size_t MB = 1024 * 1024;
    ushort_t* Bq   = (ushort_t*)(p + 0 * MB);
    ushort_t* Bk   = (ushort_t*)(p + 8 * MB);
    ushort_t* Bv   = (ushort_t*)(p + 24 * MB);
    ushort_t* Ba   = (ushort_t*)(p + 40 * MB);
    ushort_t* Bh   = (ushort_t*)(p + 48 * MB);
    ushort_t* Bx1  = (ushort_t*)(p + 56 * MB);
    ushort_t* Bx2  = (ushort_t*)(p + 64 * MB);
    ushort_t* Bi   = Bk;                        // [8,40) during FFN
    ushort_t* Xctx = Ba;                        // [40,56) early only
    ushort_t* Xin  = Bx2;                       // [64,72) early only
    ushort_t* WtA  = (ushort_t*)(p + 56 * MB);  // cross W^T: cq
    ushort_t* WtB  = (ushort_t*)(p + 58 * MB);  //            ck
    ushort_t* WtC  = (ushort_t*)(p + 60 * MB);  //            cv
    ushort_t* WtCO = (ushort_t*)(p + 62 * MB);  //            co (dies at cross-LN)
    ushort_t* WtD  = (ushort_t*)(p + 64 * MB);  // self  W^T: sq
    ushort_t* WtE  = (ushort_t*)(p + 66 * MB);  //            sk
    ushort_t* WtF  = (ushort_t*)(p + 68 * MB);  //            sv
    ushort_t* WtH  = (ushort_t*)(p + 70 * MB);  //            so (dies at self-LN)
    ushort_t* WtG  = (ushort_t*)(p + 0 * MB);   // FFN W^T scratch (8 MB)

    const float scale2 = 0.125f * LOG2E;        // base-2 softmax scale
    dim3 blk(256);

    // ---- activation conversions ----
    cvt_bf16_kernel<<<2048, blk, 0, stream>>>(input, Xin, 524288);
    cvt_bf16_kernel<<<4096, blk, 0, stream>>>(ctx, Xctx, 1048576);

    // ---- cross attention ----
    wconv4_kernel<<<dim3(32, 32, 4), blk, 0, stream>>>(
        cq_w, ck_w, cv_w, co_w, WtA, WtB, WtC, WtCO, 1024, 1024);
    // merged cq (Xin, M=4096) + ck/cv (Xctx, M=8192) in one z=3 launch
    gemm_bt_kernel<0, 128, 64, 64><<<dim3(16, 64, 3), blk, 0, stream>>>(
        Xin, Xctx, 4096, 8192, WtA, WtB, WtC, cq_b, ck_b, cv_b,
        Bq, Bk, Bv, 1024, 1024);
    mfma_attn_kernel<<<dim3(16, 64), blk, 0, stream>>>(Bq, Bk, Bv, mask, Ba, 1024, 2048, scale2);
    gemm_bt_kernel<0, 128, 64, 64><<<dim3(16, 32, 1), blk, 0, stream>>>(
        Ba, Ba, 4096, 4096, WtCO, WtCO, WtCO, co_b, co_b, co_b,
        Bh, Bh, Bh, 1024, 1024);
    ln_kernel<true, false><<<dim3(4096), blk, 0, stream>>>(Bh, input, co_g, co_be, Bx1);

    // ---- self attention ----
    wconv4_kernel<<<dim3(32, 32, 4), blk, 0, stream>>>(
        sq_w, sk_w, sv_w, so_w, WtD, WtE, WtF, WtH, 1024, 1024);
    gemm_bt_kernel<0, 128, 64, 64><<<dim3(16, 32, 3), blk, 0, stream>>>(
        Bx1, Bx1, 4096, 4096, WtD, WtE, WtF, sq_b, sk_b, sv_b,
        Bq, Bk, Bv, 1024, 1024);
    mfma_attn_kernel<<<dim3(16, 64), blk, 0, stream>>>(Bq, Bk, Bv, nullptr, Ba, 1024, 1024, scale2);
    gemm_bt_kernel<0, 128, 64, 64><<<dim3(16, 32, 1), blk, 0, stream>>>(
        Ba, Ba, 4096, 4096, WtH, WtH, WtH, so_b, so_b, so_b,
        Bh, Bh, Bh, 1024, 1024);
    ln_kernel<false, false><<<dim3(4096), blk, 0, stream>>>(Bh, Bx1, so_g, so_be, Bx2);

    // ---- FFN ----
    wconv_kernel<<<dim3(32, 128), blk, 0, stream>>>(fi_w, WtG, 1024, 4096);
    gemm_bt_kernel<2, 128, 128, 32><<<dim3(32, 32, 1), blk, 0, stream>>>(
        Bx2, Bx2, 4096, 4096, WtG, WtG, WtG, fi_b, fi_b, fi_b,
        Bi, Bi, Bi, 4096, 1024);
    wconv_kernel<<<dim3(128, 32), blk, 0, stream>>>(fo_w, WtG, 4096, 1024);
    gemm_bt_kernel<0, 128, 64, 64><<<dim3(16, 32, 1), blk, 0, stream>>>(
        Bi, Bi, 4096, 4096, WtG, WtG, WtG, fo_b, fo_b, fo_b,
        Bh, Bh, Bh, 1024, 4096);
    ln_kernel<false, true><<<dim3(4096), blk, 0, stream>>>(Bh, Bx2, fo_g, fo_be, (float*)d_out);
}